// Round 13
// baseline (155.514 us; speedup 1.0000x reference)
//
#include <hip/hip_runtime.h>
#include <math.h>

#define L_SEQ 16384
#define H_DIM 1024
#define P_DIM 512
#define N2P   1024
#define KDIM  1024
#define NKT2  32     // KDIM / 32
#define CHUNK 64
#define NCHUNK 256   // L_SEQ / CHUNK

typedef __attribute__((ext_vector_type(8))) short short8;
typedef __attribute__((ext_vector_type(4))) float f32x4;

__device__ __forceinline__ unsigned short f2bf(float f){
    unsigned int u = __float_as_uint(f);
    u = (u + 0x7FFFu + ((u >> 16) & 1u)) >> 16;
    return (unsigned short)u;
}

// ---------------- prep ----------------
__global__ void k_prep_lambda(const float* __restrict__ lre, const float* __restrict__ lim,
                              const float* __restrict__ lstep,
                              float* __restrict__ lam, float* __restrict__ coef,
                              float* __restrict__ lpow)
{
    int p = threadIdx.x;
    double step = exp((double)lstep[p]);
    double dr = (double)lre[p], di = (double)lim[p];
    double ar = dr*step, ai = di*step;
    double er = exp(ar);
    double lbr = er*cos(ai), lbi = er*sin(ai);
    lam[2*p] = (float)lbr; lam[2*p+1] = (float)lbi;
    double nr = lbr - 1.0, ni = lbi;
    double d2 = dr*dr + di*di;
    coef[2*p]   = (float)((nr*dr + ni*di)/d2);
    coef[2*p+1] = (float)((ni*dr - nr*di)/d2);
    double xr = lbr, xi = lbi;
    #pragma unroll
    for (int s=0;s<6;s++){ double t = xr*xr - xi*xi; xi = 2.0*xr*xi; xr = t; } // ^64
    lpow[2*p] = (float)xr; lpow[2*p+1] = (float)xi;
}

__global__ __launch_bounds__(256)
void k_prep_bc(const float* __restrict__ B, const float* __restrict__ C,
               const float* __restrict__ coef,
               unsigned short* __restrict__ BB, unsigned short* __restrict__ CC)
{
    int bid = blockIdx.x;
    if (bid < 2048){
        int i = bid*256 + threadIdx.x;   // i = p*H + h
        int p = i >> 10, h = i & 1023;
        float br = B[2*i], bi = B[2*i+1];
        float cr = coef[2*p], ci = coef[2*p+1];
        BB[(size_t)(2*p)*H_DIM + h]   = f2bf(cr*br - ci*bi);
        BB[(size_t)(2*p+1)*H_DIM + h] = f2bf(cr*bi + ci*br);
    } else {
        int i = (bid-2048)*256 + threadIdx.x;   // i = h*P + p
        int h = i >> 9, p = i & 511;
        float cr = C[2*i], ci = C[2*i+1];
        CC[(size_t)h*N2P + 2*p]     = f2bf(2.f*cr);
        CC[(size_t)h*N2P + 2*p + 1] = f2bf(-2.f*ci);
    }
}

// ---------------- GEMM: 128x128, BK=32, 4-slot LDS ring, depth-2, 2 blocks/CU ----
// C[M][1024] = A[M][1024]bf16 @ Bm[1024][1024]bf16^T
// CAST=1 (gemm1): A from fp32 u, cast fused into reg-staging; bf16 out to Cb.
// CAST=0 (gemm2): A,B via global_load_lds; fp32 out to Cf += Dv[col]*U32[idx].
// Ring: slot (kt+2)&3 staged at iter kt; last read at iter kt-2 (two barriers
// back) -> race-free. Each wave waits vmcnt(8) (CAST: the write_a32 implicit
// drain) BEFORE the barrier, so at release all waves' slot-kt bytes are in LDS
// (m201 counted-wait-then-barrier discipline).
// Swizzle (both sides, 0 conflicts measured R4): phys 16B-chunk = logical ^ ((row>>1)&3).
template<int CAST>
__global__ __launch_bounds__(256, 2)
void gemm128(const unsigned short* __restrict__ A16, const float* __restrict__ A32,
             const unsigned short* __restrict__ Bm,
             float* __restrict__ Cf, unsigned short* __restrict__ Cb,
             const float* __restrict__ Dv, const float* __restrict__ U32)
{
    __shared__ char lds[65536];                      // 4 slots x 16KB (A 8KB | B 8KB)
    const int tid  = threadIdx.x;
    const int lane = tid & 63;
    const int wid  = tid >> 6;
    const int wm = wid >> 1, wn = wid & 1;           // 2(M) x 2(N), wave = 64x64
    const int wg = ((int)blockIdx.x & 7) * 128 + ((int)blockIdx.x >> 3);  // XCD swizzle
    const int tm = wg >> 3, tn = wg & 7;
    const int lr = lane & 15;

    // staging: thread covers row tid>>2 (0..63; +64 for 2nd gload), phys chunk tid&3;
    // dst linear tid*16; logical source chunk = (tid&3) ^ ((row>>1)&3) = (tid&3)^((tid>>3)&3)
    const int srow = tid >> 2;
    const int scol = ((tid & 3) ^ ((tid >> 3) & 3)) << 3;   // ushort units
    // reads: row R = w*64 + m*16 + lr; byte = R*64 + ((lane>>4)^((R>>1)&3))*16
    const int kc   = (((lane >> 4) ^ ((lr >> 1) & 3)) << 4);
    const int aOff = wm*4096 + lr*64 + kc;                  // + m*1024
    const int bOff = 8192 + wn*4096 + lr*64 + kc;           // + n*1024

#define GLOAD(SRC, DST) __builtin_amdgcn_global_load_lds( \
        (const __attribute__((address_space(1))) void*)(SRC), \
        (__attribute__((address_space(3))) void*)(DST), 16, 0, 0)
#define RD(OFF) (*(const short8*)(lds + (OFF)))
#define MFMA(a,b,c) __builtin_amdgcn_mfma_f32_16x16x32_bf16(a,b,c,0,0,0)
#define ABAR  asm volatile("s_barrier" ::: "memory")

    // src kt_ may be a tail dummy; slot_ is always the ring slot (kt+2)&3
    auto stage_b = [&](int kt_, int slot_){
        char* d_ = lds + (slot_<<14) + 8192 + tid*16;
        const unsigned short* sb = Bm + (size_t)(tn*128 + srow)*KDIM + (size_t)kt_*32 + scol;
        GLOAD(sb,                   d_);
        GLOAD(sb + (size_t)64*KDIM, d_ + 4096);
    };
    auto stage_a16 = [&](int kt_, int slot_){
        char* d_ = lds + (slot_<<14) + tid*16;
        const unsigned short* sa = A16 + (size_t)(tm*128 + srow)*KDIM + (size_t)kt_*32 + scol;
        GLOAD(sa,                   d_);
        GLOAD(sa + (size_t)64*KDIM, d_ + 4096);
    };
    float4 av[2][2];
    auto load_a32 = [&](int kt_){
        #pragma unroll
        for (int g=0; g<2; ++g){
            const float* sa = A32 + (size_t)(tm*128 + g*64 + srow)*KDIM + (size_t)kt_*32 + scol;
            av[g][0] = *reinterpret_cast<const float4*>(sa);
            av[g][1] = *reinterpret_cast<const float4*>(sa + 4);
        }
    };
    auto write_a32 = [&](int slot_){
        #pragma unroll
        for (int g=0; g<2; ++g){
            union { short8 v; unsigned short s[8]; } r;
            r.s[0]=f2bf(av[g][0].x); r.s[1]=f2bf(av[g][0].y);
            r.s[2]=f2bf(av[g][0].z); r.s[3]=f2bf(av[g][0].w);
            r.s[4]=f2bf(av[g][1].x); r.s[5]=f2bf(av[g][1].y);
            r.s[6]=f2bf(av[g][1].z); r.s[7]=f2bf(av[g][1].w);
            *reinterpret_cast<short8*>(lds + (slot_<<14) + g*4096 + tid*16) = r.v;
        }
    };

    f32x4 acc[4][4];
    #pragma unroll
    for (int m=0;m<4;m++)
        #pragma unroll
        for (int n=0;n<4;n++) acc[m][n] = (f32x4){0.f,0.f,0.f,0.f};

    // prologue: slots 0,1 staged (depth 2)
    if (CAST){
        load_a32(0); stage_b(0,0); write_a32(0);   // write's implicit vmcnt drains av(0)
        load_a32(1); stage_b(1,1); write_a32(1);   // ... and B(0); leaves B(1) in flight
        asm volatile("s_waitcnt lgkmcnt(0)" ::: "memory");   // publish ds_writes
    } else {
        stage_a16(0,0); stage_b(0,0); stage_a16(1,1); stage_b(1,1);
    }

    #pragma unroll 4
    for (int kt = 0; kt < NKT2; ++kt) {
        const int sb   = (kt & 3) << 14;
        const int slot = (kt + 2) & 3;
        const int tt   = (kt+2 < NKT2) ? kt+2 : NKT2-1;  // tail dummy src, never-read slot
        if (CAST){
            load_a32(tt);        // av first (so write's implicit drain leaves only B)
            stage_b(tt, slot);
            asm volatile("s_waitcnt lgkmcnt(0)" ::: "memory");  // publish prev write_a32
        } else {
            stage_a16(tt, slot);
            stage_b(tt, slot);
            // retire own slot-kt stages before rendezvous: outstanding = kt+1(4)+kt+2(4)
            asm volatile("s_waitcnt vmcnt(8)" ::: "memory");
        }
        ABAR;   // at release: all waves' slot-kt bytes landed

        short8 afr[4], bfr[4];
        #pragma unroll
        for (int m=0;m<4;m++) afr[m] = RD(sb + aOff + m*1024);
        #pragma unroll
        for (int n=0;n<4;n++) bfr[n] = RD(sb + bOff + n*1024);
        #pragma unroll
        for (int m=0;m<4;m++)
            #pragma unroll
            for (int n=0;n<4;n++) acc[m][n] = MFMA(afr[m], bfr[n], acc[m][n]);

        if (CAST) write_a32(slot);   // implicit vmcnt wait on av retires B(kt+1) too
    }
    asm volatile("s_waitcnt vmcnt(0) lgkmcnt(0)" ::: "memory");  // drain tail dummies

    const int orow0 = tm*128 + wm*64 + (lane>>4)*4;
    const int ocol0 = tn*128 + wn*64 + lr;
    #pragma unroll
    for (int m=0;m<4;m++){
        #pragma unroll
        for (int n=0;n<4;n++){
            int row = orow0 + m*16, col = ocol0 + n*16;
            #pragma unroll
            for (int j=0;j<4;j++){
                size_t idx = (size_t)(row + j)*N2P + col;
                if (CAST) Cb[idx] = f2bf(acc[m][n][j]);
                else      Cf[idx] = acc[m][n][j] + Dv[col]*U32[idx];
            }
        }
    }
#undef GLOAD
#undef RD
#undef MFMA
#undef ABAR
}

// ---------------- scan phase 1: per-(chunk, p) aggregate (Bu in bf16 pairs) -------
__global__ __launch_bounds__(512)
void k_agg(const unsigned int* __restrict__ Bu, const float* __restrict__ lam,
           float* __restrict__ agg)
{
    int p = threadIdx.x, c = blockIdx.x;
    float lrr = lam[2*p], lii = lam[2*p+1];
    float xr = 0.f, xi = 0.f;
    const unsigned int* b2 = Bu + (size_t)c*CHUNK*512 + p;
    #pragma unroll 4
    for (int t=0;t<CHUNK;t++){
        unsigned int b = b2[(size_t)t*512];
        float br = __uint_as_float(b << 16);
        float bi = __uint_as_float(b & 0xffff0000u);
        float tr = lrr*xr - lii*xi + br;
        xi = lrr*xi + lii*xr + bi;
        xr = tr;
    }
    agg[((size_t)c*P_DIM + p)*2]     = xr;
    agg[((size_t)c*P_DIM + p)*2 + 1] = xi;
}

// ---------------- scan phase 2: Kogge-Stone over chunks ---------------------
__global__ __launch_bounds__(256)
void k_scan(const float* __restrict__ agg, const float* __restrict__ lpow,
            float* __restrict__ xinit)
{
    __shared__ float sr[NCHUNK], si[NCHUNK];
    int c = threadIdx.x, p = blockIdx.x;
    float xr = agg[((size_t)c*P_DIM + p)*2];
    float xi = agg[((size_t)c*P_DIM + p)*2 + 1];
    sr[c] = xr; si[c] = xi;
    float wr = lpow[2*p], wi = lpow[2*p+1];
    for (int s=1; s<NCHUNK; s<<=1){
        __syncthreads();
        float ur = 0.f, ui = 0.f;
        if (c >= s){ ur = sr[c-s]; ui = si[c-s]; }
        __syncthreads();
        xr += wr*ur - wi*ui;
        xi += wr*ui + wi*ur;
        sr[c] = xr; si[c] = xi;
        float t = wr*wr - wi*wi; wi = 2.f*wr*wi; wr = t;
    }
    __syncthreads();
    float er = 0.f, ei = 0.f;
    if (c > 0){ er = sr[c-1]; ei = si[c-1]; }
    xinit[((size_t)c*P_DIM + p)*2]     = er;
    xinit[((size_t)c*P_DIM + p)*2 + 1] = ei;
}

// ---------------- scan phase 3: apply + emit bf16 pairs ----------------------
__global__ __launch_bounds__(512)
void k_apply(const unsigned int* __restrict__ Bu, const float* __restrict__ lam,
             const float* __restrict__ xinit, unsigned int* __restrict__ xs)
{
    int p = threadIdx.x, c = blockIdx.x;
    float lrr = lam[2*p], lii = lam[2*p+1];
    float xr = xinit[((size_t)c*P_DIM + p)*2];
    float xi = xinit[((size_t)c*P_DIM + p)*2 + 1];
    const unsigned int* b2 = Bu + (size_t)c*CHUNK*512 + p;
    unsigned int* o = xs + (size_t)c*CHUNK*512 + p;
    #pragma unroll 4
    for (int t=0;t<CHUNK;t++){
        unsigned int b = b2[(size_t)t*512];
        float br = __uint_as_float(b << 16);
        float bi = __uint_as_float(b & 0xffff0000u);
        float tr = lrr*xr - lii*xi + br;
        xi = lrr*xi + lii*xr + bi;
        xr = tr;
        o[(size_t)t*512] = (unsigned int)f2bf(xr) | ((unsigned int)f2bf(xi) << 16);
    }
}

extern "C" void kernel_launch(void* const* d_in, const int* in_sizes, int n_in,
                              void* d_out, int out_size, void* d_ws, size_t ws_size,
                              hipStream_t stream)
{
    const float* u   = (const float*)d_in[0];
    const float* lre = (const float*)d_in[1];
    const float* lim = (const float*)d_in[2];
    const float* B   = (const float*)d_in[3];
    const float* C   = (const float*)d_in[4];
    const float* D   = (const float*)d_in[5];
    const float* ls  = (const float*)d_in[6];
    float* out = (float*)d_out;

    char* w = (char*)d_ws;
    unsigned short* xs16 = (unsigned short*)(w + 0);          // 32 MiB
    unsigned short* Bu16 = (unsigned short*)(w + 33554432);   // 32 MiB
    unsigned short* BB   = (unsigned short*)(w + 67108864);   // 2 MiB
    unsigned short* CC   = (unsigned short*)(w + 69206016);   // 2 MiB
    float* lam   = (float*)(w + 71303168);
    float* coef  = (float*)(w + 71307264);
    float* lpow  = (float*)(w + 71311360);
    float* agg   = (float*)(w + 71315456);                    // 1 MiB
    float* xinit = (float*)(w + 72364032);                    // 1 MiB

    k_prep_lambda<<<1, P_DIM, 0, stream>>>(lre, lim, ls, lam, coef, lpow);
    k_prep_bc<<<4096, 256, 0, stream>>>(B, C, coef, BB, CC);

    // gemm1: Bu16 = bf16( u @ BB^T ), u-cast fused into A-staging
    gemm128<1><<<1024, 256, 0, stream>>>(nullptr, u, BB, nullptr, Bu16, nullptr, nullptr);

    k_agg<<<NCHUNK, P_DIM, 0, stream>>>((const unsigned int*)Bu16, lam, agg);
    k_scan<<<P_DIM, NCHUNK, 0, stream>>>(agg, lpow, xinit);
    k_apply<<<NCHUNK, P_DIM, 0, stream>>>((const unsigned int*)Bu16, lam, xinit,
                                          (unsigned int*)xs16);

    // gemm2: out = xs16 @ CC^T + D*u   (fp32 u in epilogue)
    gemm128<0><<<1024, 256, 0, stream>>>(xs16, nullptr, CC, out, nullptr, D, u);
}

// Round 14
// 140.387 us; speedup vs baseline: 1.1077x; 1.1077x over previous
//
#include <hip/hip_runtime.h>
#include <math.h>

#define L_SEQ 16384
#define H_DIM 1024
#define P_DIM 512
#define N2P   1024
#define KDIM  1024
#define NKT   16     // KDIM / 64
#define CHUNK 64
#define NCHUNK 256   // L_SEQ / CHUNK

typedef __attribute__((ext_vector_type(8))) short short8;
typedef __attribute__((ext_vector_type(4))) float f32x4;

__device__ __forceinline__ unsigned short f2bf(float f){
    unsigned int u = __float_as_uint(f);
    u = (u + 0x7FFFu + ((u >> 16) & 1u)) >> 16;
    return (unsigned short)u;
}

// ---------------- prep ----------------
__global__ void k_prep_lambda(const float* __restrict__ lre, const float* __restrict__ lim,
                              const float* __restrict__ lstep,
                              float* __restrict__ lam, float* __restrict__ coef,
                              float* __restrict__ lpow)
{
    int p = threadIdx.x;
    double step = exp((double)lstep[p]);
    double dr = (double)lre[p], di = (double)lim[p];
    double ar = dr*step, ai = di*step;
    double er = exp(ar);
    double lbr = er*cos(ai), lbi = er*sin(ai);
    lam[2*p] = (float)lbr; lam[2*p+1] = (float)lbi;
    double nr = lbr - 1.0, ni = lbi;
    double d2 = dr*dr + di*di;
    coef[2*p]   = (float)((nr*dr + ni*di)/d2);
    coef[2*p+1] = (float)((ni*dr - nr*di)/d2);
    double xr = lbr, xi = lbi;
    #pragma unroll
    for (int s=0;s<6;s++){ double t = xr*xr - xi*xi; xi = 2.0*xr*xi; xr = t; } // ^64
    lpow[2*p] = (float)xr; lpow[2*p+1] = (float)xi;
}

__global__ __launch_bounds__(256)
void k_prep_bc(const float* __restrict__ B, const float* __restrict__ C,
               const float* __restrict__ coef,
               unsigned short* __restrict__ BB, unsigned short* __restrict__ CC)
{
    int bid = blockIdx.x;
    if (bid < 2048){
        int i = bid*256 + threadIdx.x;   // i = p*H + h
        int p = i >> 10, h = i & 1023;
        float br = B[2*i], bi = B[2*i+1];
        float cr = coef[2*p], ci = coef[2*p+1];
        BB[(size_t)(2*p)*H_DIM + h]   = f2bf(cr*br - ci*bi);
        BB[(size_t)(2*p+1)*H_DIM + h] = f2bf(cr*bi + ci*br);
    } else {
        int i = (bid-2048)*256 + threadIdx.x;   // i = h*P + p
        int h = i >> 9, p = i & 511;
        float cr = C[2*i], ci = C[2*i+1];
        CC[(size_t)h*N2P + 2*p]     = f2bf(2.f*cr);
        CC[(size_t)h*N2P + 2*p + 1] = f2bf(-2.f*ci);
    }
}

// ---------------- GEMM: 128x128, BK=64, 2-parity dbuf, race-free depth-2 ----------
// C[M][1024] = A[M][1024]bf16 @ Bm[1024][1024]bf16^T
// CAST=1 (gemm1): A from fp32 u (cast fused into reg-staging); bf16 out to Cb.
// CAST=0 (gemm2): A,B via global_load_lds; fp32 out to Cf += Dv[col]*U32[idx].
// Per KT (parity P = kt&1):
//   [CAST: issue av loads for kt+2]
//   vmcnt(N)   -- slot-kt stages retired (N = younger in-flight ops, FIFO-traced)
//   ABAR(rv1)  -- slot-kt bytes visible to all waves
//   16 ds_reads (plain derefs); lgkmcnt(0)  -- own reads COMPLETED (data in VGPRs)
//   ABAR(rv2)  -- ALL waves' reads of parity P retired -> P may be overwritten
//   STAGE(kt+2) into parity P   (provably race-free; ~1.5-2 KT issue->consume)
//   32 MFMA (pure-reg; waves desync)   [CAST: + write_a32 after MFMA]
// 64KB LDS -> 2 resident blocks/CU; grid 1024 = 2 resident x 2 sequential (epilogue
// overlap). Swizzle (both sides, 0 conflicts R11): phys 16B-chunk = logical ^ (row&7).
template<int CAST>
__global__ __launch_bounds__(256, 2)
void gemm128(const unsigned short* __restrict__ A16, const float* __restrict__ A32,
             const unsigned short* __restrict__ Bm,
             float* __restrict__ Cf, unsigned short* __restrict__ Cb,
             const float* __restrict__ Dv, const float* __restrict__ U32)
{
    __shared__ char lds[65536];          // parity p: A at p*32768, B at p*32768+16384
    const int tid  = threadIdx.x;
    const int lane = tid & 63;
    const int wid  = tid >> 6;
    const int wm = wid >> 1, wn = wid & 1;           // 2(M) x 2(N), wave = 64x64
    const int wg = ((int)blockIdx.x & 7) * 128 + ((int)blockIdx.x >> 3);  // XCD swizzle
    const int tm = wg >> 3, tn = wg & 7;
    const int lr = lane & 15;

    // staging: pass g covers row g*32 + (tid>>3), phys chunk tid&7 (dst byte g*4096+tid*16);
    // source logical chunk = (tid&7)^(row&7)
    const int srow = tid >> 3;                               // 0..31
    const int scol = ((tid & 7) ^ ((tid >> 3) & 7)) << 3;    // element units
    // reads: row R; byte = R*128 + ((g|4ks)^(R&7))*16, R&7 == lr&7
    const int kc0 = (((lane >> 4)      ^ (lr & 7)) << 4);
    const int kc1 = ((((lane >> 4) | 4) ^ (lr & 7)) << 4);
    const int aOff = (wm*64 + lr)*128;                       // + m*2048 + kc
    const int bOff = 16384 + (wn*64 + lr)*128;               // + n*2048 + kc

#define GLOAD(SRC, DST) __builtin_amdgcn_global_load_lds( \
        (const __attribute__((address_space(1))) void*)(SRC), \
        (__attribute__((address_space(3))) void*)(DST), 16, 0, 0)
#define RD(OFF) (*(const short8*)(lds + (OFF)))
#define MFMA(a,b,c) __builtin_amdgcn_mfma_f32_16x16x32_bf16(a,b,c,0,0,0)
#define ABAR  asm volatile("s_barrier" ::: "memory")

    auto stage_b = [&](int kt_){
        char* d_ = lds + ((kt_&1)<<15) + 16384 + tid*16;
        const unsigned short* sb = Bm + (size_t)(tn*128 + srow)*KDIM + (size_t)kt_*64 + scol;
        GLOAD(sb,                    d_);
        GLOAD(sb + (size_t)32*KDIM,  d_ + 4096);
        GLOAD(sb + (size_t)64*KDIM,  d_ + 8192);
        GLOAD(sb + (size_t)96*KDIM,  d_ + 12288);
    };
    auto stage_a16 = [&](int kt_){
        char* d_ = lds + ((kt_&1)<<15) + tid*16;
        const unsigned short* sa = A16 + (size_t)(tm*128 + srow)*KDIM + (size_t)kt_*64 + scol;
        GLOAD(sa,                    d_);
        GLOAD(sa + (size_t)32*KDIM,  d_ + 4096);
        GLOAD(sa + (size_t)64*KDIM,  d_ + 8192);
        GLOAD(sa + (size_t)96*KDIM,  d_ + 12288);
    };
    float4 av[4][2];                    // 8 global fp32x4 loads per slot
    auto load_a32 = [&](int kt_){
        #pragma unroll
        for (int g=0; g<4; ++g){
            const float* sa = A32 + (size_t)(tm*128 + g*32 + srow)*KDIM + (size_t)kt_*64 + scol;
            av[g][0] = *reinterpret_cast<const float4*>(sa);
            av[g][1] = *reinterpret_cast<const float4*>(sa + 4);
        }
    };
    auto write_a32 = [&](int kt_){      // implicit vmcnt wait on av before use
        #pragma unroll
        for (int g=0; g<4; ++g){
            union { short8 v; unsigned short s[8]; } r;
            r.s[0]=f2bf(av[g][0].x); r.s[1]=f2bf(av[g][0].y);
            r.s[2]=f2bf(av[g][0].z); r.s[3]=f2bf(av[g][0].w);
            r.s[4]=f2bf(av[g][1].x); r.s[5]=f2bf(av[g][1].y);
            r.s[6]=f2bf(av[g][1].z); r.s[7]=f2bf(av[g][1].w);
            *reinterpret_cast<short8*>(lds + ((kt_&1)<<15) + g*4096 + tid*16) = r.v;
        }
    };

    f32x4 acc[4][4];
    #pragma unroll
    for (int m=0;m<4;m++)
        #pragma unroll
        for (int n=0;n<4;n++) acc[m][n] = (f32x4){0.f,0.f,0.f,0.f};

    // prologue: slots 0,1
    if (CAST){
        load_a32(0); write_a32(0); stage_b(0);
        load_a32(1); write_a32(1); stage_b(1);
        asm volatile("s_waitcnt lgkmcnt(0)" ::: "memory");   // publish ds_writes
    } else {
        stage_a16(0); stage_b(0); stage_a16(1); stage_b(1);
    }

    for (int kt = 0; kt < NKT; ++kt) {
        const int sb = (kt & 1) << 15;
        const int tt = (kt+2 < NKT) ? kt+2 : NKT-1;   // tail dummy (never-read slot)
        if (CAST){
            load_a32(tt);   // 8 vm loads to regs; no LDS touch (race-free anywhere)
            // FIFO: B(kt) retired by write_a32(kt+1)'s implicit av-wait last iter;
            // vmcnt(12) = B(kt+1)4 + av(kt+2)8 younger — harmless belt-and-braces.
            asm volatile("s_waitcnt vmcnt(12)" ::: "memory");
        } else {
            // outstanding: slot kt+1's 8; anything older (slot kt) must retire.
            asm volatile("s_waitcnt vmcnt(8)" ::: "memory");
        }
        ABAR;   // rv1: slot-kt bytes visible to all waves

        short8 a0[4], b0[4], a1v[4], b1v[4];
        #pragma unroll
        for (int m=0;m<4;m++) a0[m]  = RD(sb + aOff + m*2048 + kc0);
        #pragma unroll
        for (int n=0;n<4;n++) b0[n]  = RD(sb + bOff + n*2048 + kc0);
        #pragma unroll
        for (int m=0;m<4;m++) a1v[m] = RD(sb + aOff + m*2048 + kc1);
        #pragma unroll
        for (int n=0;n<4;n++) b1v[n] = RD(sb + bOff + n*2048 + kc1);
        asm volatile("s_waitcnt lgkmcnt(0)" ::: "memory");  // own reads COMPLETED (+publishes own ds_writes)
        ABAR;   // rv2: all waves' reads of parity P retired -> P free

        if (CAST){
            stage_b(tt);            // into parity P (safe after rv2)
        } else {
            stage_a16(tt); stage_b(tt);
        }
        #pragma unroll
        for (int m=0;m<4;m++)
            #pragma unroll
            for (int n=0;n<4;n++) acc[m][n] = MFMA(a0[m], b0[n], acc[m][n]);
        #pragma unroll
        for (int m=0;m<4;m++)
            #pragma unroll
            for (int n=0;n<4;n++) acc[m][n] = MFMA(a1v[m], b1v[n], acc[m][n]);
        if (CAST) write_a32(tt);    // ds_writes into parity P after MFMA (av covered)
    }
    asm volatile("s_waitcnt vmcnt(0) lgkmcnt(0)" ::: "memory");  // drain tail dummies

    const int orow0 = tm*128 + wm*64 + (lane>>4)*4;
    const int ocol0 = tn*128 + wn*64 + lr;
    #pragma unroll
    for (int m=0;m<4;m++){
        #pragma unroll
        for (int n=0;n<4;n++){
            int row = orow0 + m*16, col = ocol0 + n*16;
            #pragma unroll
            for (int j=0;j<4;j++){
                size_t idx = (size_t)(row + j)*N2P + col;
                if (CAST) Cb[idx] = f2bf(acc[m][n][j]);
                else      Cf[idx] = acc[m][n][j] + Dv[col]*U32[idx];
            }
        }
    }
#undef GLOAD
#undef RD
#undef MFMA
#undef ABAR
}

// ---------------- scan phase 1: per-(chunk, p) aggregate (Bu in bf16 pairs) -------
__global__ __launch_bounds__(512)
void k_agg(const unsigned int* __restrict__ Bu, const float* __restrict__ lam,
           float* __restrict__ agg)
{
    int p = threadIdx.x, c = blockIdx.x;
    float lrr = lam[2*p], lii = lam[2*p+1];
    float xr = 0.f, xi = 0.f;
    const unsigned int* b2 = Bu + (size_t)c*CHUNK*512 + p;
    #pragma unroll 4
    for (int t=0;t<CHUNK;t++){
        unsigned int b = b2[(size_t)t*512];
        float br = __uint_as_float(b << 16);
        float bi = __uint_as_float(b & 0xffff0000u);
        float tr = lrr*xr - lii*xi + br;
        xi = lrr*xi + lii*xr + bi;
        xr = tr;
    }
    agg[((size_t)c*P_DIM + p)*2]     = xr;
    agg[((size_t)c*P_DIM + p)*2 + 1] = xi;
}

// ---------------- scan phase 2: Kogge-Stone over chunks ---------------------
__global__ __launch_bounds__(256)
void k_scan(const float* __restrict__ agg, const float* __restrict__ lpow,
            float* __restrict__ xinit)
{
    __shared__ float sr[NCHUNK], si[NCHUNK];
    int c = threadIdx.x, p = blockIdx.x;
    float xr = agg[((size_t)c*P_DIM + p)*2];
    float xi = agg[((size_t)c*P_DIM + p)*2 + 1];
    sr[c] = xr; si[c] = xi;
    float wr = lpow[2*p], wi = lpow[2*p+1];
    for (int s=1; s<NCHUNK; s<<=1){
        __syncthreads();
        float ur = 0.f, ui = 0.f;
        if (c >= s){ ur = sr[c-s]; ui = si[c-s]; }
        __syncthreads();
        xr += wr*ur - wi*ui;
        xi += wr*ui + wi*ur;
        sr[c] = xr; si[c] = xi;
        float t = wr*wr - wi*wi; wi = 2.f*wr*wi; wr = t;
    }
    __syncthreads();
    float er = 0.f, ei = 0.f;
    if (c > 0){ er = sr[c-1]; ei = si[c-1]; }
    xinit[((size_t)c*P_DIM + p)*2]     = er;
    xinit[((size_t)c*P_DIM + p)*2 + 1] = ei;
}

// ---------------- scan phase 3: apply + emit bf16 pairs ----------------------
__global__ __launch_bounds__(512)
void k_apply(const unsigned int* __restrict__ Bu, const float* __restrict__ lam,
             const float* __restrict__ xinit, unsigned int* __restrict__ xs)
{
    int p = threadIdx.x, c = blockIdx.x;
    float lrr = lam[2*p], lii = lam[2*p+1];
    float xr = xinit[((size_t)c*P_DIM + p)*2];
    float xi = xinit[((size_t)c*P_DIM + p)*2 + 1];
    const unsigned int* b2 = Bu + (size_t)c*CHUNK*512 + p;
    unsigned int* o = xs + (size_t)c*CHUNK*512 + p;
    #pragma unroll 4
    for (int t=0;t<CHUNK;t++){
        unsigned int b = b2[(size_t)t*512];
        float br = __uint_as_float(b << 16);
        float bi = __uint_as_float(b & 0xffff0000u);
        float tr = lrr*xr - lii*xi + br;
        xi = lrr*xi + lii*xr + bi;
        xr = tr;
        o[(size_t)t*512] = (unsigned int)f2bf(xr) | ((unsigned int)f2bf(xi) << 16);
    }
}

extern "C" void kernel_launch(void* const* d_in, const int* in_sizes, int n_in,
                              void* d_out, int out_size, void* d_ws, size_t ws_size,
                              hipStream_t stream)
{
    const float* u   = (const float*)d_in[0];
    const float* lre = (const float*)d_in[1];
    const float* lim = (const float*)d_in[2];
    const float* B   = (const float*)d_in[3];
    const float* C   = (const float*)d_in[4];
    const float* D   = (const float*)d_in[5];
    const float* ls  = (const float*)d_in[6];
    float* out = (float*)d_out;

    char* w = (char*)d_ws;
    unsigned short* xs16 = (unsigned short*)(w + 0);          // 32 MiB
    unsigned short* Bu16 = (unsigned short*)(w + 33554432);   // 32 MiB
    unsigned short* BB   = (unsigned short*)(w + 67108864);   // 2 MiB
    unsigned short* CC   = (unsigned short*)(w + 69206016);   // 2 MiB
    float* lam   = (float*)(w + 71303168);
    float* coef  = (float*)(w + 71307264);
    float* lpow  = (float*)(w + 71311360);
    float* agg   = (float*)(w + 71315456);                    // 1 MiB
    float* xinit = (float*)(w + 72364032);                    // 1 MiB

    k_prep_lambda<<<1, P_DIM, 0, stream>>>(lre, lim, ls, lam, coef, lpow);
    k_prep_bc<<<4096, 256, 0, stream>>>(B, C, coef, BB, CC);

    // gemm1: Bu16 = bf16( u @ BB^T ), u-cast fused into A-staging
    gemm128<1><<<1024, 256, 0, stream>>>(nullptr, u, BB, nullptr, Bu16, nullptr, nullptr);

    k_agg<<<NCHUNK, P_DIM, 0, stream>>>((const unsigned int*)Bu16, lam, agg);
    k_scan<<<P_DIM, NCHUNK, 0, stream>>>(agg, lpow, xinit);
    k_apply<<<NCHUNK, P_DIM, 0, stream>>>((const unsigned int*)Bu16, lam, xinit,
                                          (unsigned int*)xs16);

    // gemm2: out = xs16 @ CC^T + D*u   (fp32 u in epilogue)
    gemm128<0><<<1024, 256, 0, stream>>>(xs16, nullptr, CC, out, nullptr, D, u);
}

// Round 15
// 128.008 us; speedup vs baseline: 1.2149x; 1.0967x over previous
//
#include <hip/hip_runtime.h>
#include <math.h>

#define L_SEQ 16384
#define H_DIM 1024
#define P_DIM 512
#define N2P   1024
#define KDIM  1024
#define NKT   16     // KDIM / 64 K-tiles
#define CHUNK 64
#define NCHUNK 256   // L_SEQ / CHUNK

typedef __attribute__((ext_vector_type(8))) short short8;
typedef __attribute__((ext_vector_type(4))) float f32x4;
typedef __attribute__((address_space(3))) const char* lds3_t;

__device__ __forceinline__ unsigned short f2bf(float f){
    unsigned int u = __float_as_uint(f);
    u = (u + 0x7FFFu + ((u >> 16) & 1u)) >> 16;
    return (unsigned short)u;
}
__device__ __forceinline__ float bf2f(unsigned int lo16){
    return __uint_as_float(lo16 << 16);
}

// ---------------- prep ----------------
__global__ void k_prep_lambda(const float* __restrict__ lre, const float* __restrict__ lim,
                              const float* __restrict__ lstep,
                              float* __restrict__ lam, float* __restrict__ coef,
                              float* __restrict__ lpow)
{
    int p = threadIdx.x;
    double step = exp((double)lstep[p]);
    double dr = (double)lre[p], di = (double)lim[p];
    double ar = dr*step, ai = di*step;
    double er = exp(ar);
    double lbr = er*cos(ai), lbi = er*sin(ai);
    lam[2*p] = (float)lbr; lam[2*p+1] = (float)lbi;
    double nr = lbr - 1.0, ni = lbi;
    double d2 = dr*dr + di*di;
    coef[2*p]   = (float)((nr*dr + ni*di)/d2);
    coef[2*p+1] = (float)((ni*dr - nr*di)/d2);
    double xr = lbr, xi = lbi;
    #pragma unroll
    for (int s=0;s<6;s++){ double t = xr*xr - xi*xi; xi = 2.0*xr*xi; xr = t; } // ^64
    lpow[2*p] = (float)xr; lpow[2*p+1] = (float)xi;
}

// merged BB + CC prep: bid<2048 -> BB, else CC
__global__ __launch_bounds__(256)
void k_prep_bc(const float* __restrict__ B, const float* __restrict__ C,
               const float* __restrict__ coef,
               unsigned short* __restrict__ BB, unsigned short* __restrict__ CC)
{
    int bid = blockIdx.x;
    if (bid < 2048){
        int i = bid*256 + threadIdx.x;   // i = p*H + h
        int p = i >> 10, h = i & 1023;
        float br = B[2*i], bi = B[2*i+1];
        float cr = coef[2*p], ci = coef[2*p+1];
        BB[(size_t)(2*p)*H_DIM + h]   = f2bf(cr*br - ci*bi);
        BB[(size_t)(2*p+1)*H_DIM + h] = f2bf(cr*bi + ci*br);
    } else {
        int i = (bid-2048)*256 + threadIdx.x;   // i = h*P + p
        int h = i >> 9, p = i & 511;
        float cr = C[2*i], ci = C[2*i+1];
        CC[(size_t)h*N2P + 2*p]     = f2bf(2.f*cr);
        CC[(size_t)h*N2P + 2*p + 1] = f2bf(-2.f*ci);
    }
}

__global__ __launch_bounds__(256)
void k_cast(const float4* __restrict__ u, unsigned short* __restrict__ o)
{
    int i = blockIdx.x*256 + threadIdx.x;
    float4 a = u[2*i], b = u[2*i+1];
    union { short8 v; unsigned short s[8]; } r;
    r.s[0]=f2bf(a.x); r.s[1]=f2bf(a.y); r.s[2]=f2bf(a.z); r.s[3]=f2bf(a.w);
    r.s[4]=f2bf(b.x); r.s[5]=f2bf(b.y); r.s[6]=f2bf(b.z); r.s[7]=f2bf(b.w);
    *reinterpret_cast<short8*>(o + (size_t)i*8) = r.v;
}

// ---------------- GEMM (R7, verified best): 256x256, BK=64, quadrant-pipelined ----
// C[M][1024] = A[M][1024]bf16 @ Bm[1024][1024]bf16^T
// Per K-tile: DSR(Q1:8) STAGE_A(kt+1) DSR(Q2:4) lgkm(4) MFMA Q1 | DSR(Q3:8)
// lgkm(8) MFMA Q2 | DSR(Q4:4) lgkm(4) BAR(mid) STAGE_B(kt+2) MFMA Q3 | lgkm(0)
// MFMA Q4 | vmcnt(4) BAR(end).  Counted lgkm streams next-quadrant reads under
// current MFMAs; vmcnt never drains to 0 in the loop; mid-BAR legalizes B-slot
// overwrite (B(kt) reads retired by pre-bar lgkm(4)).
// Swizzle (both sides, 0 conflicts measured): phys 16B-chunk = logical ^ (row&7).
template<int EPI>
__global__ __launch_bounds__(512, 2)
void gemm256(const unsigned short* __restrict__ A, const unsigned short* __restrict__ Bm,
             float* __restrict__ Cf, unsigned short* __restrict__ Cb,
             const float* __restrict__ Dv, const unsigned short* __restrict__ U16)
{
    __shared__ char lds[131072];
    const int tid  = threadIdx.x;
    const int lane = tid & 63;
    const int wid  = tid >> 6;
    const int wm = wid >> 2, wn = wid & 3;          // 2(M) x 4(N) waves
    const int wg = ((int)blockIdx.x & 7) * 32 + ((int)blockIdx.x >> 3);  // XCD swizzle
    const int tm = wg >> 2, tn = wg & 3;
    const int lr = lane & 15;

    const int scol = ((tid & 7) ^ ((tid >> 3) & 7)) << 3;   // ushort units, pre-swizzled
    const int srow = tid >> 3;                               // 0..63
    const int kc0 = (((lane >> 4)      ^ (lr & 7)) << 4);
    const int kc1 = ((((lane >> 4) | 4) ^ (lr & 7)) << 4);
    const int aSub = wm*16384 + lr*128;
    const int bSub = 32768 + (wn >> 1)*16384 + (wn & 1)*8192 + lr*128;

#define GLOAD(SRC, DST) __builtin_amdgcn_global_load_lds( \
        (const __attribute__((address_space(1))) void*)(SRC), \
        (__attribute__((address_space(3))) void*)(DST), 16, 0, 0)
#define STAGE_A(kt_, h_) do{ \
    char* d_ = lds + (((kt_)&1)<<16) + (h_)*16384 + tid*16; \
    const unsigned short* s_ = A + (size_t)(tm*256 + (h_)*128 + srow)*KDIM + (size_t)(kt_)*64 + scol; \
    GLOAD(s_, d_); GLOAD(s_ + (size_t)64*KDIM, d_ + 8192); }while(0)
#define STAGE_B(kt_, h_) do{ \
    char* d_ = lds + (((kt_)&1)<<16) + 32768 + (h_)*16384 + tid*16; \
    const unsigned short* s_ = Bm + (size_t)(tn*256 + (h_)*128 + srow)*KDIM + (size_t)(kt_)*64 + scol; \
    GLOAD(s_, d_); GLOAD(s_ + (size_t)64*KDIM, d_ + 8192); }while(0)
#define DSR(D, P, IMM) asm volatile("ds_read_b128 %0, %1 offset:" IMM : "=v"(D) : "v"(P))
#define LGKM(N) do{ asm volatile("s_waitcnt lgkmcnt(" #N ")" ::: "memory"); \
                    __builtin_amdgcn_sched_barrier(0); }while(0)
#define VMC4  asm volatile("s_waitcnt vmcnt(4)" ::: "memory")
#define ABAR  asm volatile("s_barrier" ::: "memory")
#define SB0   __builtin_amdgcn_sched_barrier(0)
#define MFMA(a,b,c) __builtin_amdgcn_mfma_f32_16x16x32_bf16(a,b,c,0,0,0)
#define PRIO1 __builtin_amdgcn_s_setprio(1)
#define PRIO0 __builtin_amdgcn_s_setprio(0)

    short8 a1[4], a2[4], bb0[4], bb1[4];
    f32x4 acc[8][4];
    #pragma unroll
    for (int m=0;m<8;m++)
        #pragma unroll
        for (int n=0;n<4;n++) acc[m][n] = (f32x4){0.f,0.f,0.f,0.f};

    STAGE_A(0,0); STAGE_A(0,1); STAGE_B(0,0); STAGE_B(0,1); STAGE_B(1,0); STAGE_B(1,1);
    VMC4; ABAR;

    #pragma unroll 2
    for (int kt = 0; kt < NKT; ++kt) {
        const int sb = (kt & 1) << 16;
        const int tA = (kt+1 < NKT) ? kt+1 : NKT-1;
        const int tB = (kt+2 < NKT) ? kt+2 : NKT-1;
        lds3_t pa0 = (lds3_t)(lds + sb + aSub + kc0);
        lds3_t pa1 = (lds3_t)(lds + sb + aSub + kc1);
        lds3_t pb0 = (lds3_t)(lds + sb + bSub + kc0);
        lds3_t pb1 = (lds3_t)(lds + sb + bSub + kc1);

        DSR(a1[0], pa0, "0");    DSR(a1[1], pa0, "2048");
        DSR(a1[2], pa0, "4096"); DSR(a1[3], pa0, "6144");
        DSR(bb0[0], pb0, "0");    DSR(bb0[1], pb0, "2048");
        DSR(bb0[2], pb0, "4096"); DSR(bb0[3], pb0, "6144");
        STAGE_A(tA, 0); STAGE_A(tA, 1);
        DSR(a2[0], pa0, "8192");  DSR(a2[1], pa0, "10240");
        DSR(a2[2], pa0, "12288"); DSR(a2[3], pa0, "14336");
        LGKM(4);
        PRIO1;
        #pragma unroll
        for (int m=0;m<4;m++)
            #pragma unroll
            for (int n=0;n<4;n++) acc[m][n] = MFMA(a1[m], bb0[n], acc[m][n]);
        PRIO0; SB0;
        DSR(a1[0], pa1, "0");    DSR(a1[1], pa1, "2048");
        DSR(a1[2], pa1, "4096"); DSR(a1[3], pa1, "6144");
        DSR(bb1[0], pb1, "0");    DSR(bb1[1], pb1, "2048");
        DSR(bb1[2], pb1, "4096"); DSR(bb1[3], pb1, "6144");
        LGKM(8);
        PRIO1;
        #pragma unroll
        for (int m=0;m<4;m++)
            #pragma unroll
            for (int n=0;n<4;n++) acc[4+m][n] = MFMA(a2[m], bb0[n], acc[4+m][n]);
        PRIO0; SB0;
        DSR(a2[0], pa1, "8192");  DSR(a2[1], pa1, "10240");
        DSR(a2[2], pa1, "12288"); DSR(a2[3], pa1, "14336");
        LGKM(4);
        ABAR;
        STAGE_B(tB, 0); STAGE_B(tB, 1);
        PRIO1;
        #pragma unroll
        for (int m=0;m<4;m++)
            #pragma unroll
            for (int n=0;n<4;n++) acc[m][n] = MFMA(a1[m], bb1[n], acc[m][n]);
        PRIO0; SB0;
        LGKM(0);
        PRIO1;
        #pragma unroll
        for (int m=0;m<4;m++)
            #pragma unroll
            for (int n=0;n<4;n++) acc[4+m][n] = MFMA(a2[m], bb1[n], acc[4+m][n]);
        PRIO0; SB0;
        VMC4;
        ABAR;
    }
    asm volatile("s_waitcnt vmcnt(0)" ::: "memory");

    const int orow0 = tm*256 + wm*128 + (lane>>4)*4;
    const int ocol0 = tn*256 + wn*64 + lr;
    #pragma unroll
    for (int m=0;m<8;m++){
        #pragma unroll
        for (int n=0;n<4;n++){
            int row = orow0 + m*16, col = ocol0 + n*16;
            #pragma unroll
            for (int j=0;j<4;j++){
                size_t idx = (size_t)(row + j)*N2P + col;
                if (EPI) Cf[idx] = acc[m][n][j] + Dv[col]*bf2f(U16[idx]);
                else     Cb[idx] = f2bf(acc[m][n][j]);
            }
        }
    }
#undef GLOAD
#undef STAGE_A
#undef STAGE_B
#undef DSR
#undef LGKM
#undef VMC4
#undef ABAR
#undef SB0
#undef MFMA
#undef PRIO1
#undef PRIO0
}

// ---------------- scan phase 1: per-(chunk, p) aggregate (Bu in bf16 pairs) -------
__global__ __launch_bounds__(512)
void k_agg(const unsigned int* __restrict__ Bu, const float* __restrict__ lam,
           float* __restrict__ agg)
{
    int p = threadIdx.x, c = blockIdx.x;
    float lrr = lam[2*p], lii = lam[2*p+1];
    float xr = 0.f, xi = 0.f;
    const unsigned int* b2 = Bu + (size_t)c*CHUNK*512 + p;
    #pragma unroll 4
    for (int t=0;t<CHUNK;t++){
        unsigned int b = b2[(size_t)t*512];
        float br = __uint_as_float(b << 16);
        float bi = __uint_as_float(b & 0xffff0000u);
        float tr = lrr*xr - lii*xi + br;
        xi = lrr*xi + lii*xr + bi;
        xr = tr;
    }
    agg[((size_t)c*P_DIM + p)*2]     = xr;
    agg[((size_t)c*P_DIM + p)*2 + 1] = xi;
}

// ---------------- scan phase 2: Kogge-Stone over chunks ---------------------
__global__ __launch_bounds__(256)
void k_scan(const float* __restrict__ agg, const float* __restrict__ lpow,
            float* __restrict__ xinit)
{
    __shared__ float sr[NCHUNK], si[NCHUNK];
    int c = threadIdx.x, p = blockIdx.x;
    float xr = agg[((size_t)c*P_DIM + p)*2];
    float xi = agg[((size_t)c*P_DIM + p)*2 + 1];
    sr[c] = xr; si[c] = xi;
    float wr = lpow[2*p], wi = lpow[2*p+1];
    for (int s=1; s<NCHUNK; s<<=1){
        __syncthreads();
        float ur = 0.f, ui = 0.f;
        if (c >= s){ ur = sr[c-s]; ui = si[c-s]; }
        __syncthreads();
        xr += wr*ur - wi*ui;
        xi += wr*ui + wi*ur;
        sr[c] = xr; si[c] = xi;
        float t = wr*wr - wi*wi; wi = 2.f*wr*wi; wr = t;
    }
    __syncthreads();
    float er = 0.f, ei = 0.f;
    if (c > 0){ er = sr[c-1]; ei = si[c-1]; }
    xinit[((size_t)c*P_DIM + p)*2]     = er;
    xinit[((size_t)c*P_DIM + p)*2 + 1] = ei;
}

// ---------------- scan phase 3: apply + emit bf16 pairs ----------------------
__global__ __launch_bounds__(512)
void k_apply(const unsigned int* __restrict__ Bu, const float* __restrict__ lam,
             const float* __restrict__ xinit, unsigned int* __restrict__ xs)
{
    int p = threadIdx.x, c = blockIdx.x;
    float lrr = lam[2*p], lii = lam[2*p+1];
    float xr = xinit[((size_t)c*P_DIM + p)*2];
    float xi = xinit[((size_t)c*P_DIM + p)*2 + 1];
    const unsigned int* b2 = Bu + (size_t)c*CHUNK*512 + p;
    unsigned int* o = xs + (size_t)c*CHUNK*512 + p;
    #pragma unroll 4
    for (int t=0;t<CHUNK;t++){
        unsigned int b = b2[(size_t)t*512];
        float br = __uint_as_float(b << 16);
        float bi = __uint_as_float(b & 0xffff0000u);
        float tr = lrr*xr - lii*xi + br;
        xi = lrr*xi + lii*xr + bi;
        xr = tr;
        o[(size_t)t*512] = (unsigned int)f2bf(xr) | ((unsigned int)f2bf(xi) << 16);
    }
}

extern "C" void kernel_launch(void* const* d_in, const int* in_sizes, int n_in,
                              void* d_out, int out_size, void* d_ws, size_t ws_size,
                              hipStream_t stream)
{
    const float* u   = (const float*)d_in[0];
    const float* lre = (const float*)d_in[1];
    const float* lim = (const float*)d_in[2];
    const float* B   = (const float*)d_in[3];
    const float* C   = (const float*)d_in[4];
    const float* D   = (const float*)d_in[5];
    const float* ls  = (const float*)d_in[6];
    float* out = (float*)d_out;

    char* w = (char*)d_ws;
    unsigned short* u16  = (unsigned short*)(w + 0);          // 32 MiB
    unsigned short* xs16 = (unsigned short*)(w + 33554432);   // 32 MiB
    unsigned short* Bu16 = (unsigned short*)(w + 67108864);   // 32 MiB
    unsigned short* BB   = (unsigned short*)(w + 100663296);  // 2 MiB
    unsigned short* CC   = (unsigned short*)(w + 102760448);  // 2 MiB
    float* lam   = (float*)(w + 104857600);
    float* coef  = (float*)(w + 104861696);
    float* lpow  = (float*)(w + 104865792);
    float* agg   = (float*)(w + 104869888);                   // 1 MiB
    float* xinit = (float*)(w + 105918464);                   // 1 MiB

    k_prep_lambda<<<1, P_DIM, 0, stream>>>(lre, lim, ls, lam, coef, lpow);
    k_prep_bc<<<4096, 256, 0, stream>>>(B, C, coef, BB, CC);
    k_cast<<<(L_SEQ*H_DIM)/(256*8), 256, 0, stream>>>((const float4*)u, u16);

    gemm256<0><<<256, 512, 0, stream>>>(u16, BB, nullptr, Bu16, nullptr, nullptr);

    k_agg<<<NCHUNK, P_DIM, 0, stream>>>((const unsigned int*)Bu16, lam, agg);
    k_scan<<<P_DIM, NCHUNK, 0, stream>>>(agg, lpow, xinit);
    k_apply<<<NCHUNK, P_DIM, 0, stream>>>((const unsigned int*)Bu16, lam, xinit,
                                          (unsigned int*)xs16);

    gemm256<1><<<256, 512, 0, stream>>>(xs16, CC, out, nullptr, D, u16);
}

// Round 16
// 124.915 us; speedup vs baseline: 1.2450x; 1.0248x over previous
//
#include <hip/hip_runtime.h>
#include <math.h>

#define L_SEQ 16384
#define H_DIM 1024
#define P_DIM 512
#define N2P   1024
#define KDIM  1024
#define NKT   16     // KDIM / 64 K-tiles
#define CHUNK 64
#define NCHUNK 256   // L_SEQ / CHUNK

typedef __attribute__((ext_vector_type(8))) short short8;
typedef __attribute__((ext_vector_type(4))) float f32x4;
typedef __attribute__((address_space(3))) const char* lds3_t;

__device__ __forceinline__ unsigned short f2bf(float f){
    unsigned int u = __float_as_uint(f);
    u = (u + 0x7FFFu + ((u >> 16) & 1u)) >> 16;
    return (unsigned short)u;
}
__device__ __forceinline__ float bf2f(unsigned int lo16){
    return __uint_as_float(lo16 << 16);
}

// ---------------- prep: lambda, coef, lambda^64, and weight table wtab[t][p]=λ^(63-t) --
__global__ void k_prep_lambda(const float* __restrict__ lre, const float* __restrict__ lim,
                              const float* __restrict__ lstep,
                              float* __restrict__ lam, float* __restrict__ coef,
                              float* __restrict__ lpow, float* __restrict__ wtab)
{
    int p = threadIdx.x;
    double step = exp((double)lstep[p]);
    double dr = (double)lre[p], di = (double)lim[p];
    double ar = dr*step, ai = di*step;
    double er = exp(ar);
    double lbr = er*cos(ai), lbi = er*sin(ai);
    lam[2*p] = (float)lbr; lam[2*p+1] = (float)lbi;
    double nr = lbr - 1.0, ni = lbi;
    double d2 = dr*dr + di*di;
    coef[2*p]   = (float)((nr*dr + ni*di)/d2);
    coef[2*p+1] = (float)((ni*dr - nr*di)/d2);
    // wtab[t][p] = λ^(63-t), t=0..63  (weights for the fused chunk-aggregate)
    double pwr = 1.0, pwi = 0.0;
    for (int tt = 63; tt >= 0; --tt){
        wtab[((size_t)tt*P_DIM + p)*2]     = (float)pwr;
        wtab[((size_t)tt*P_DIM + p)*2 + 1] = (float)pwi;
        double t2 = pwr*lbr - pwi*lbi;
        pwi = pwr*lbi + pwi*lbr;
        pwr = t2;
    }
    double xr = lbr, xi = lbi;
    #pragma unroll
    for (int s=0;s<6;s++){ double t = xr*xr - xi*xi; xi = 2.0*xr*xi; xr = t; } // ^64
    lpow[2*p] = (float)xr; lpow[2*p+1] = (float)xi;
}

// merged BB + CC prep: bid<2048 -> BB, else CC
__global__ __launch_bounds__(256)
void k_prep_bc(const float* __restrict__ B, const float* __restrict__ C,
               const float* __restrict__ coef,
               unsigned short* __restrict__ BB, unsigned short* __restrict__ CC)
{
    int bid = blockIdx.x;
    if (bid < 2048){
        int i = bid*256 + threadIdx.x;   // i = p*H + h
        int p = i >> 10, h = i & 1023;
        float br = B[2*i], bi = B[2*i+1];
        float cr = coef[2*p], ci = coef[2*p+1];
        BB[(size_t)(2*p)*H_DIM + h]   = f2bf(cr*br - ci*bi);
        BB[(size_t)(2*p+1)*H_DIM + h] = f2bf(cr*bi + ci*br);
    } else {
        int i = (bid-2048)*256 + threadIdx.x;   // i = h*P + p
        int h = i >> 9, p = i & 511;
        float cr = C[2*i], ci = C[2*i+1];
        CC[(size_t)h*N2P + 2*p]     = f2bf(2.f*cr);
        CC[(size_t)h*N2P + 2*p + 1] = f2bf(-2.f*ci);
    }
}

__global__ __launch_bounds__(256)
void k_cast(const float4* __restrict__ u, unsigned short* __restrict__ o)
{
    int i = blockIdx.x*256 + threadIdx.x;
    float4 a = u[2*i], b = u[2*i+1];
    union { short8 v; unsigned short s[8]; } r;
    r.s[0]=f2bf(a.x); r.s[1]=f2bf(a.y); r.s[2]=f2bf(a.z); r.s[3]=f2bf(a.w);
    r.s[4]=f2bf(b.x); r.s[5]=f2bf(b.y); r.s[6]=f2bf(b.z); r.s[7]=f2bf(b.w);
    *reinterpret_cast<short8*>(o + (size_t)i*8) = r.v;
}

// ---------------- GEMM (R7 schedule, verified best): 256x256, BK=64 ---------------
// EPI=0 (gemm1): bf16 out to Cb + FUSED chunk-aggregate (replaces k_agg):
//   block rows = 4 complete chunks, block cols = 128 p's -> agg computed from acc.
// EPI=1 (gemm2): fp32 out to Cf += Dv[col]*bf16(U16).
template<int EPI>
__global__ __launch_bounds__(512, 2)
void gemm256(const unsigned short* __restrict__ A, const unsigned short* __restrict__ Bm,
             float* __restrict__ Cf, unsigned short* __restrict__ Cb,
             const float* __restrict__ Dv, const unsigned short* __restrict__ U16,
             const float* __restrict__ wtab, float* __restrict__ aggOut)
{
    __shared__ char lds[131072];
    const int tid  = threadIdx.x;
    const int lane = tid & 63;
    const int wid  = tid >> 6;
    const int wm = wid >> 2, wn = wid & 3;          // 2(M) x 4(N) waves
    const int wg = ((int)blockIdx.x & 7) * 32 + ((int)blockIdx.x >> 3);  // XCD swizzle
    const int tm = wg >> 2, tn = wg & 3;
    const int lr = lane & 15;

    const int scol = ((tid & 7) ^ ((tid >> 3) & 7)) << 3;   // ushort units, pre-swizzled
    const int srow = tid >> 3;                               // 0..63
    const int kc0 = (((lane >> 4)      ^ (lr & 7)) << 4);
    const int kc1 = ((((lane >> 4) | 4) ^ (lr & 7)) << 4);
    const int aSub = wm*16384 + lr*128;
    const int bSub = 32768 + (wn >> 1)*16384 + (wn & 1)*8192 + lr*128;

#define GLOAD(SRC, DST) __builtin_amdgcn_global_load_lds( \
        (const __attribute__((address_space(1))) void*)(SRC), \
        (__attribute__((address_space(3))) void*)(DST), 16, 0, 0)
#define STAGE_A(kt_, h_) do{ \
    char* d_ = lds + (((kt_)&1)<<16) + (h_)*16384 + tid*16; \
    const unsigned short* s_ = A + (size_t)(tm*256 + (h_)*128 + srow)*KDIM + (size_t)(kt_)*64 + scol; \
    GLOAD(s_, d_); GLOAD(s_ + (size_t)64*KDIM, d_ + 8192); }while(0)
#define STAGE_B(kt_, h_) do{ \
    char* d_ = lds + (((kt_)&1)<<16) + 32768 + (h_)*16384 + tid*16; \
    const unsigned short* s_ = Bm + (size_t)(tn*256 + (h_)*128 + srow)*KDIM + (size_t)(kt_)*64 + scol; \
    GLOAD(s_, d_); GLOAD(s_ + (size_t)64*KDIM, d_ + 8192); }while(0)
#define DSR(D, P, IMM) asm volatile("ds_read_b128 %0, %1 offset:" IMM : "=v"(D) : "v"(P))
#define LGKM(N) do{ asm volatile("s_waitcnt lgkmcnt(" #N ")" ::: "memory"); \
                    __builtin_amdgcn_sched_barrier(0); }while(0)
#define VMC4  asm volatile("s_waitcnt vmcnt(4)" ::: "memory")
#define ABAR  asm volatile("s_barrier" ::: "memory")
#define SB0   __builtin_amdgcn_sched_barrier(0)
#define MFMA(a,b,c) __builtin_amdgcn_mfma_f32_16x16x32_bf16(a,b,c,0,0,0)
#define PRIO1 __builtin_amdgcn_s_setprio(1)
#define PRIO0 __builtin_amdgcn_s_setprio(0)

    short8 a1[4], a2[4], bb0[4], bb1[4];
    f32x4 acc[8][4];
    #pragma unroll
    for (int m=0;m<8;m++)
        #pragma unroll
        for (int n=0;n<4;n++) acc[m][n] = (f32x4){0.f,0.f,0.f,0.f};

    STAGE_A(0,0); STAGE_A(0,1); STAGE_B(0,0); STAGE_B(0,1); STAGE_B(1,0); STAGE_B(1,1);
    VMC4; ABAR;

    #pragma unroll 2
    for (int kt = 0; kt < NKT; ++kt) {
        const int sb = (kt & 1) << 16;
        const int tA = (kt+1 < NKT) ? kt+1 : NKT-1;
        const int tB = (kt+2 < NKT) ? kt+2 : NKT-1;
        lds3_t pa0 = (lds3_t)(lds + sb + aSub + kc0);
        lds3_t pa1 = (lds3_t)(lds + sb + aSub + kc1);
        lds3_t pb0 = (lds3_t)(lds + sb + bSub + kc0);
        lds3_t pb1 = (lds3_t)(lds + sb + bSub + kc1);

        DSR(a1[0], pa0, "0");    DSR(a1[1], pa0, "2048");
        DSR(a1[2], pa0, "4096"); DSR(a1[3], pa0, "6144");
        DSR(bb0[0], pb0, "0");    DSR(bb0[1], pb0, "2048");
        DSR(bb0[2], pb0, "4096"); DSR(bb0[3], pb0, "6144");
        STAGE_A(tA, 0); STAGE_A(tA, 1);
        DSR(a2[0], pa0, "8192");  DSR(a2[1], pa0, "10240");
        DSR(a2[2], pa0, "12288"); DSR(a2[3], pa0, "14336");
        LGKM(4);
        PRIO1;
        #pragma unroll
        for (int m=0;m<4;m++)
            #pragma unroll
            for (int n=0;n<4;n++) acc[m][n] = MFMA(a1[m], bb0[n], acc[m][n]);
        PRIO0; SB0;
        DSR(a1[0], pa1, "0");    DSR(a1[1], pa1, "2048");
        DSR(a1[2], pa1, "4096"); DSR(a1[3], pa1, "6144");
        DSR(bb1[0], pb1, "0");    DSR(bb1[1], pb1, "2048");
        DSR(bb1[2], pb1, "4096"); DSR(bb1[3], pb1, "6144");
        LGKM(8);
        PRIO1;
        #pragma unroll
        for (int m=0;m<4;m++)
            #pragma unroll
            for (int n=0;n<4;n++) acc[4+m][n] = MFMA(a2[m], bb0[n], acc[4+m][n]);
        PRIO0; SB0;
        DSR(a2[0], pa1, "8192");  DSR(a2[1], pa1, "10240");
        DSR(a2[2], pa1, "12288"); DSR(a2[3], pa1, "14336");
        LGKM(4);
        ABAR;
        STAGE_B(tB, 0); STAGE_B(tB, 1);
        PRIO1;
        #pragma unroll
        for (int m=0;m<4;m++)
            #pragma unroll
            for (int n=0;n<4;n++) acc[m][n] = MFMA(a1[m], bb1[n], acc[m][n]);
        PRIO0; SB0;
        LGKM(0);
        PRIO1;
        #pragma unroll
        for (int m=0;m<4;m++)
            #pragma unroll
            for (int n=0;n<4;n++) acc[4+m][n] = MFMA(a2[m], bb1[n], acc[4+m][n]);
        PRIO0; SB0;
        VMC4;
        ABAR;
    }
    asm volatile("s_waitcnt vmcnt(0)" ::: "memory");

    // ---------------- fused chunk-aggregate (gemm1 only) --------------------------
    // agg[c][p] = sum_t λ_p^(63-t) * Bu[c*64+t][p].  Lane's rows: wm*128+m*16+q*4+j
    // (q=lane>>4) -> chunk = 4tm+2wm+(m>=4), t = (m&3)*16+q*4+j.  Lane's col parity
    // (lr&1) selects re/im component; combine across partner lane via shfl_xor(1),
    // across q via shfl_xor(16/32).
    if (!EPI){
        const int q = lane >> 4;
        #pragma unroll
        for (int n=0;n<4;n++){
            const int pg = tn*128 + wn*32 + n*8 + (lr >> 1);   // global p for this col pair
            float wr[16], wi[16];
            #pragma unroll
            for (int mm=0;mm<4;mm++)
                #pragma unroll
                for (int j=0;j<4;j++){
                    const float* wp = wtab + ((size_t)(mm*16 + q*4 + j)*P_DIM + pg)*2;
                    wr[mm*4+j] = wp[0]; wi[mm*4+j] = wp[1];
                }
            #pragma unroll
            for (int h=0; h<2; h++){
                float s1 = 0.f, s2 = 0.f;
                #pragma unroll
                for (int mm=0;mm<4;mm++)
                    #pragma unroll
                    for (int j=0;j<4;j++){
                        float x = acc[h*4+mm][n][j];
                        s1 += wr[mm*4+j]*x;
                        s2 += wi[mm*4+j]*x;
                    }
                s1 += __shfl_xor(s1,16); s1 += __shfl_xor(s1,32);
                s2 += __shfl_xor(s2,16); s2 += __shfl_xor(s2,32);
                float s1p = __shfl_xor(s1,1);
                float s2p = __shfl_xor(s2,1);
                if (lane < 16 && !(lr & 1)){
                    int c = 4*tm + 2*wm + h;
                    float* o = aggOut + ((size_t)c*P_DIM + pg)*2;
                    o[0] = s1 - s2p;      // re: Σ wr·re − Σ wi·im
                    o[1] = s2 + s1p;      // im: Σ wi·re + Σ wr·im
                }
            }
        }
    }

    const int orow0 = tm*256 + wm*128 + (lane>>4)*4;
    const int ocol0 = tn*256 + wn*64 + lr;
    #pragma unroll
    for (int m=0;m<8;m++){
        #pragma unroll
        for (int n=0;n<4;n++){
            int row = orow0 + m*16, col = ocol0 + n*16;
            #pragma unroll
            for (int j=0;j<4;j++){
                size_t idx = (size_t)(row + j)*N2P + col;
                if (EPI) Cf[idx] = acc[m][n][j] + Dv[col]*bf2f(U16[idx]);
                else     Cb[idx] = f2bf(acc[m][n][j]);
            }
        }
    }
#undef GLOAD
#undef STAGE_A
#undef STAGE_B
#undef DSR
#undef LGKM
#undef VMC4
#undef ABAR
#undef SB0
#undef MFMA
#undef PRIO1
#undef PRIO0
}

// ---------------- scan phase 2: Kogge-Stone over chunks (xinit written IN PLACE) --
__global__ __launch_bounds__(256)
void k_scan(float* __restrict__ agg, const float* __restrict__ lpow)
{
    __shared__ float sr[NCHUNK], si[NCHUNK];
    int c = threadIdx.x, p = blockIdx.x;
    float xr = agg[((size_t)c*P_DIM + p)*2];
    float xi = agg[((size_t)c*P_DIM + p)*2 + 1];
    sr[c] = xr; si[c] = xi;
    float wr = lpow[2*p], wi = lpow[2*p+1];
    for (int s=1; s<NCHUNK; s<<=1){
        __syncthreads();
        float ur = 0.f, ui = 0.f;
        if (c >= s){ ur = sr[c-s]; ui = si[c-s]; }
        __syncthreads();
        xr += wr*ur - wi*ui;
        xi += wr*ui + wi*ur;
        sr[c] = xr; si[c] = xi;
        float t = wr*wr - wi*wi; wi = 2.f*wr*wi; wr = t;
    }
    __syncthreads();
    float er = 0.f, ei = 0.f;
    if (c > 0){ er = sr[c-1]; ei = si[c-1]; }
    // in-place: block p only touches column p; all reads happened before stores
    agg[((size_t)c*P_DIM + p)*2]     = er;
    agg[((size_t)c*P_DIM + p)*2 + 1] = ei;
}

// ---------------- scan phase 3: apply + emit bf16 pairs ----------------------
__global__ __launch_bounds__(512)
void k_apply(const unsigned int* __restrict__ Bu, const float* __restrict__ lam,
             const float* __restrict__ xinit, unsigned int* __restrict__ xs)
{
    int p = threadIdx.x, c = blockIdx.x;
    float lrr = lam[2*p], lii = lam[2*p+1];
    float xr = xinit[((size_t)c*P_DIM + p)*2];
    float xi = xinit[((size_t)c*P_DIM + p)*2 + 1];
    const unsigned int* b2 = Bu + (size_t)c*CHUNK*512 + p;
    unsigned int* o = xs + (size_t)c*CHUNK*512 + p;
    #pragma unroll 4
    for (int t=0;t<CHUNK;t++){
        unsigned int b = b2[(size_t)t*512];
        float br = __uint_as_float(b << 16);
        float bi = __uint_as_float(b & 0xffff0000u);
        float tr = lrr*xr - lii*xi + br;
        xi = lrr*xi + lii*xr + bi;
        xr = tr;
        o[(size_t)t*512] = (unsigned int)f2bf(xr) | ((unsigned int)f2bf(xi) << 16);
    }
}

extern "C" void kernel_launch(void* const* d_in, const int* in_sizes, int n_in,
                              void* d_out, int out_size, void* d_ws, size_t ws_size,
                              hipStream_t stream)
{
    const float* u   = (const float*)d_in[0];
    const float* lre = (const float*)d_in[1];
    const float* lim = (const float*)d_in[2];
    const float* B   = (const float*)d_in[3];
    const float* C   = (const float*)d_in[4];
    const float* D   = (const float*)d_in[5];
    const float* ls  = (const float*)d_in[6];
    float* out = (float*)d_out;

    char* w = (char*)d_ws;
    unsigned short* u16  = (unsigned short*)(w + 0);          // 32 MiB
    unsigned short* xs16 = (unsigned short*)(w + 33554432);   // 32 MiB
    unsigned short* Bu16 = (unsigned short*)(w + 67108864);   // 32 MiB
    unsigned short* BB   = (unsigned short*)(w + 100663296);  // 2 MiB
    unsigned short* CC   = (unsigned short*)(w + 102760448);  // 2 MiB
    float* lam   = (float*)(w + 104857600);
    float* coef  = (float*)(w + 104861696);
    float* lpow  = (float*)(w + 104865792);
    float* agg   = (float*)(w + 104869888);                   // 1 MiB (also xinit, in place)
    float* wtab  = (float*)(w + 105918464);                   // 256 KiB: λ^(63-t) table

    k_prep_lambda<<<1, P_DIM, 0, stream>>>(lre, lim, ls, lam, coef, lpow, wtab);
    k_prep_bc<<<4096, 256, 0, stream>>>(B, C, coef, BB, CC);
    k_cast<<<(L_SEQ*H_DIM)/(256*8), 256, 0, stream>>>((const float4*)u, u16);

    // gemm1: Bu16 = bf16(u16 @ BB^T) + fused per-chunk aggregates -> agg
    gemm256<0><<<256, 512, 0, stream>>>(u16, BB, nullptr, Bu16, nullptr, nullptr,
                                        wtab, agg);

    k_scan<<<P_DIM, NCHUNK, 0, stream>>>(agg, lpow);
    k_apply<<<NCHUNK, P_DIM, 0, stream>>>((const unsigned int*)Bu16, lam, agg,
                                          (unsigned int*)xs16);

    // gemm2: out = xs16 @ CC^T + D*u
    gemm256<1><<<256, 512, 0, stream>>>(xs16, CC, out, nullptr, D, u16,
                                        nullptr, nullptr);
}

// Round 17
// 123.136 us; speedup vs baseline: 1.2629x; 1.0144x over previous
//
#include <hip/hip_runtime.h>
#include <math.h>

#define L_SEQ 16384
#define H_DIM 1024
#define P_DIM 512
#define N2P   1024
#define KDIM  1024
#define NKT   16     // KDIM / 64 K-tiles
#define CHUNK 64
#define NCHUNK 256   // L_SEQ / CHUNK

typedef __attribute__((ext_vector_type(8))) short short8;
typedef __attribute__((ext_vector_type(4))) float f32x4;
typedef __attribute__((address_space(3))) const char* lds3_t;

__device__ __forceinline__ unsigned short f2bf(float f){
    unsigned int u = __float_as_uint(f);
    u = (u + 0x7FFFu + ((u >> 16) & 1u)) >> 16;
    return (unsigned short)u;
}
__device__ __forceinline__ float bf2f(unsigned int lo16){
    return __uint_as_float(lo16 << 16);
}

// ---------------- prep: lambda, coef, lambda^64, wtab[t][p]=λ^(63-t) ----------------
__global__ void k_prep_lambda(const float* __restrict__ lre, const float* __restrict__ lim,
                              const float* __restrict__ lstep,
                              float* __restrict__ lam, float* __restrict__ coef,
                              float* __restrict__ lpow, float* __restrict__ wtab)
{
    int p = threadIdx.x;
    double step = exp((double)lstep[p]);
    double dr = (double)lre[p], di = (double)lim[p];
    double ar = dr*step, ai = di*step;
    double er = exp(ar);
    double lbr = er*cos(ai), lbi = er*sin(ai);
    lam[2*p] = (float)lbr; lam[2*p+1] = (float)lbi;
    double nr = lbr - 1.0, ni = lbi;
    double d2 = dr*dr + di*di;
    coef[2*p]   = (float)((nr*dr + ni*di)/d2);
    coef[2*p+1] = (float)((ni*dr - nr*di)/d2);
    double pwr = 1.0, pwi = 0.0;
    for (int tt = 63; tt >= 0; --tt){
        wtab[((size_t)tt*P_DIM + p)*2]     = (float)pwr;
        wtab[((size_t)tt*P_DIM + p)*2 + 1] = (float)pwi;
        double t2 = pwr*lbr - pwi*lbi;
        pwi = pwr*lbi + pwi*lbr;
        pwr = t2;
    }
    double xr = lbr, xi = lbi;
    #pragma unroll
    for (int s=0;s<6;s++){ double t = xr*xr - xi*xi; xi = 2.0*xr*xi; xr = t; } // ^64
    lpow[2*p] = (float)xr; lpow[2*p+1] = (float)xi;
}

// merged BB + CC + u-cast: one launch, grid 12288
__global__ __launch_bounds__(256)
void k_prep_misc(const float* __restrict__ B, const float* __restrict__ C,
                 const float* __restrict__ coef,
                 unsigned short* __restrict__ BB, unsigned short* __restrict__ CC,
                 const float4* __restrict__ u, unsigned short* __restrict__ u16)
{
    int bid = blockIdx.x;
    if (bid < 2048){
        int i = bid*256 + threadIdx.x;   // i = p*H + h
        int p = i >> 10, h = i & 1023;
        float br = B[2*i], bi = B[2*i+1];
        float cr = coef[2*p], ci = coef[2*p+1];
        BB[(size_t)(2*p)*H_DIM + h]   = f2bf(cr*br - ci*bi);
        BB[(size_t)(2*p+1)*H_DIM + h] = f2bf(cr*bi + ci*br);
    } else if (bid < 4096){
        int i = (bid-2048)*256 + threadIdx.x;   // i = h*P + p
        int h = i >> 9, p = i & 511;
        float cr = C[2*i], ci = C[2*i+1];
        CC[(size_t)h*N2P + 2*p]     = f2bf(2.f*cr);
        CC[(size_t)h*N2P + 2*p + 1] = f2bf(-2.f*ci);
    } else {
        int i = (bid-4096)*256 + threadIdx.x;
        float4 a = u[2*i], b = u[2*i+1];
        union { short8 v; unsigned short s[8]; } r;
        r.s[0]=f2bf(a.x); r.s[1]=f2bf(a.y); r.s[2]=f2bf(a.z); r.s[3]=f2bf(a.w);
        r.s[4]=f2bf(b.x); r.s[5]=f2bf(b.y); r.s[6]=f2bf(b.z); r.s[7]=f2bf(b.w);
        *reinterpret_cast<short8*>(u16 + (size_t)i*8) = r.v;
    }
}

// ---------------- GEMM: 256x256, BK=64, ONE barrier/KT, quadrant-pipelined ---------
// Per KT (parity P=kt&1, dest D=(kt+1)&1 — opposite, so staging needs NO mid-barrier):
//   DSR(Q1:8) STAGE_A->D DSR(Q2:4) lgkm(4) MFMA Q1 | DSR(Q3:8) STAGE_B->D lgkm(8)
//   MFMA Q2 | DSR(Q4:4) lgkm(4) MFMA Q3 | lgkm(0) MFMA Q4 | vmcnt(0) ABAR.
// vmcnt(0) is free: stages issued ~5000 cyc earlier (full-KT cover; R12's depth-1
// collapse was short-KT 128² duration, not depth). Race-free: dest parity last read
// at kt-1, all reads retired before kt-1's end ABAR.
// Swizzle (both sides, 0 conflicts measured): phys 16B-chunk = logical ^ (row&7).
template<int EPI>
__global__ __launch_bounds__(512, 2)
void gemm256(const unsigned short* __restrict__ A, const unsigned short* __restrict__ Bm,
             float* __restrict__ Cf, unsigned short* __restrict__ Cb,
             const float* __restrict__ Dv, const unsigned short* __restrict__ U16,
             const float* __restrict__ wtab, float* __restrict__ aggOut)
{
    __shared__ char lds[131072];
    const int tid  = threadIdx.x;
    const int lane = tid & 63;
    const int wid  = tid >> 6;
    const int wm = wid >> 2, wn = wid & 3;          // 2(M) x 4(N) waves
    const int wg = ((int)blockIdx.x & 7) * 32 + ((int)blockIdx.x >> 3);  // XCD swizzle
    const int tm = wg >> 2, tn = wg & 3;
    const int lr = lane & 15;

    const int scol = ((tid & 7) ^ ((tid >> 3) & 7)) << 3;   // ushort units, pre-swizzled
    const int srow = tid >> 3;                               // 0..63
    const int kc0 = (((lane >> 4)      ^ (lr & 7)) << 4);
    const int kc1 = ((((lane >> 4) | 4) ^ (lr & 7)) << 4);
    const int aSub = wm*16384 + lr*128;
    const int bSub = 32768 + (wn >> 1)*16384 + (wn & 1)*8192 + lr*128;

#define GLOAD(SRC, DST) __builtin_amdgcn_global_load_lds( \
        (const __attribute__((address_space(1))) void*)(SRC), \
        (__attribute__((address_space(3))) void*)(DST), 16, 0, 0)
#define STAGE_A(src_, par_, h_) do{ \
    char* d_ = lds + ((par_)<<16) + (h_)*16384 + tid*16; \
    const unsigned short* s_ = A + (size_t)(tm*256 + (h_)*128 + srow)*KDIM + (size_t)(src_)*64 + scol; \
    GLOAD(s_, d_); GLOAD(s_ + (size_t)64*KDIM, d_ + 8192); }while(0)
#define STAGE_B(src_, par_, h_) do{ \
    char* d_ = lds + ((par_)<<16) + 32768 + (h_)*16384 + tid*16; \
    const unsigned short* s_ = Bm + (size_t)(tn*256 + (h_)*128 + srow)*KDIM + (size_t)(src_)*64 + scol; \
    GLOAD(s_, d_); GLOAD(s_ + (size_t)64*KDIM, d_ + 8192); }while(0)
#define DSR(D, P, IMM) asm volatile("ds_read_b128 %0, %1 offset:" IMM : "=v"(D) : "v"(P))
#define LGKM(N) do{ asm volatile("s_waitcnt lgkmcnt(" #N ")" ::: "memory"); \
                    __builtin_amdgcn_sched_barrier(0); }while(0)
#define VMC0  asm volatile("s_waitcnt vmcnt(0)" ::: "memory")
#define ABAR  asm volatile("s_barrier" ::: "memory")
#define SB0   __builtin_amdgcn_sched_barrier(0)
#define MFMA(a,b,c) __builtin_amdgcn_mfma_f32_16x16x32_bf16(a,b,c,0,0,0)
#define PRIO1 __builtin_amdgcn_s_setprio(1)
#define PRIO0 __builtin_amdgcn_s_setprio(0)

    short8 a1[4], a2[4], bb0[4], bb1[4];
    f32x4 acc[8][4];
    #pragma unroll
    for (int m=0;m<8;m++)
        #pragma unroll
        for (int n=0;n<4;n++) acc[m][n] = (f32x4){0.f,0.f,0.f,0.f};

    // prologue: KT0 into parity 0, fully landed
    STAGE_A(0,0,0); STAGE_A(0,0,1); STAGE_B(0,0,0); STAGE_B(0,0,1);
    VMC0; ABAR;

    #pragma unroll 2
    for (int kt = 0; kt < NKT; ++kt) {
        const int sb   = (kt & 1) << 16;
        const int dpar = (~kt) & 1;                    // dest parity (opposite)
        const int src  = (kt+1 < NKT) ? kt+1 : NKT-1;  // tail dummy: dest parity never read
        lds3_t pa0 = (lds3_t)(lds + sb + aSub + kc0);
        lds3_t pa1 = (lds3_t)(lds + sb + aSub + kc1);
        lds3_t pb0 = (lds3_t)(lds + sb + bSub + kc0);
        lds3_t pb1 = (lds3_t)(lds + sb + bSub + kc1);

        DSR(a1[0], pa0, "0");    DSR(a1[1], pa0, "2048");
        DSR(a1[2], pa0, "4096"); DSR(a1[3], pa0, "6144");
        DSR(bb0[0], pb0, "0");    DSR(bb0[1], pb0, "2048");
        DSR(bb0[2], pb0, "4096"); DSR(bb0[3], pb0, "6144");
        STAGE_A(src, dpar, 0); STAGE_A(src, dpar, 1);
        DSR(a2[0], pa0, "8192");  DSR(a2[1], pa0, "10240");
        DSR(a2[2], pa0, "12288"); DSR(a2[3], pa0, "14336");
        LGKM(4);
        PRIO1;
        #pragma unroll
        for (int m=0;m<4;m++)
            #pragma unroll
            for (int n=0;n<4;n++) acc[m][n] = MFMA(a1[m], bb0[n], acc[m][n]);
        PRIO0; SB0;
        DSR(a1[0], pa1, "0");    DSR(a1[1], pa1, "2048");
        DSR(a1[2], pa1, "4096"); DSR(a1[3], pa1, "6144");
        DSR(bb1[0], pb1, "0");    DSR(bb1[1], pb1, "2048");
        DSR(bb1[2], pb1, "4096"); DSR(bb1[3], pb1, "6144");
        STAGE_B(src, dpar, 0); STAGE_B(src, dpar, 1);
        LGKM(8);
        PRIO1;
        #pragma unroll
        for (int m=0;m<4;m++)
            #pragma unroll
            for (int n=0;n<4;n++) acc[4+m][n] = MFMA(a2[m], bb0[n], acc[4+m][n]);
        PRIO0; SB0;
        DSR(a2[0], pa1, "8192");  DSR(a2[1], pa1, "10240");
        DSR(a2[2], pa1, "12288"); DSR(a2[3], pa1, "14336");
        LGKM(4);
        PRIO1;
        #pragma unroll
        for (int m=0;m<4;m++)
            #pragma unroll
            for (int n=0;n<4;n++) acc[m][n] = MFMA(a1[m], bb1[n], acc[m][n]);
        PRIO0; SB0;
        LGKM(0);
        PRIO1;
        #pragma unroll
        for (int m=0;m<4;m++)
            #pragma unroll
            for (int n=0;n<4;n++) acc[4+m][n] = MFMA(a2[m], bb1[n], acc[4+m][n]);
        PRIO0; SB0;
        VMC0;     // free: stages issued a full KT of work earlier
        ABAR;     // single barrier per KT
    }

    // ---------------- fused chunk-aggregate (gemm1 only) --------------------------
    if (!EPI){
        const int q = lane >> 4;
        #pragma unroll
        for (int n=0;n<4;n++){
            const int pg = tn*128 + wn*32 + n*8 + (lr >> 1);
            float wr[16], wi[16];
            #pragma unroll
            for (int mm=0;mm<4;mm++)
                #pragma unroll
                for (int j=0;j<4;j++){
                    const float* wp = wtab + ((size_t)(mm*16 + q*4 + j)*P_DIM + pg)*2;
                    wr[mm*4+j] = wp[0]; wi[mm*4+j] = wp[1];
                }
            #pragma unroll
            for (int h=0; h<2; h++){
                float s1 = 0.f, s2 = 0.f;
                #pragma unroll
                for (int mm=0;mm<4;mm++)
                    #pragma unroll
                    for (int j=0;j<4;j++){
                        float x = acc[h*4+mm][n][j];
                        s1 += wr[mm*4+j]*x;
                        s2 += wi[mm*4+j]*x;
                    }
                s1 += __shfl_xor(s1,16); s1 += __shfl_xor(s1,32);
                s2 += __shfl_xor(s2,16); s2 += __shfl_xor(s2,32);
                float s1p = __shfl_xor(s1,1);
                float s2p = __shfl_xor(s2,1);
                if (lane < 16 && !(lr & 1)){
                    int c = 4*tm + 2*wm + h;
                    float* o = aggOut + ((size_t)c*P_DIM + pg)*2;
                    o[0] = s1 - s2p;
                    o[1] = s2 + s1p;
                }
            }
        }
    }

    const int orow0 = tm*256 + wm*128 + (lane>>4)*4;
    const int ocol0 = tn*256 + wn*64 + lr;
    #pragma unroll
    for (int m=0;m<8;m++){
        #pragma unroll
        for (int n=0;n<4;n++){
            int row = orow0 + m*16, col = ocol0 + n*16;
            #pragma unroll
            for (int j=0;j<4;j++){
                size_t idx = (size_t)(row + j)*N2P + col;
                if (EPI) Cf[idx] = acc[m][n][j] + Dv[col]*bf2f(U16[idx]);
                else     Cb[idx] = f2bf(acc[m][n][j]);
            }
        }
    }
#undef GLOAD
#undef STAGE_A
#undef STAGE_B
#undef DSR
#undef LGKM
#undef VMC0
#undef ABAR
#undef SB0
#undef MFMA
#undef PRIO1
#undef PRIO0
}

// ---------------- scan phase 2: Kogge-Stone over chunks (in place) ---------------
__global__ __launch_bounds__(256)
void k_scan(float* __restrict__ agg, const float* __restrict__ lpow)
{
    __shared__ float sr[NCHUNK], si[NCHUNK];
    int c = threadIdx.x, p = blockIdx.x;
    float xr = agg[((size_t)c*P_DIM + p)*2];
    float xi = agg[((size_t)c*P_DIM + p)*2 + 1];
    sr[c] = xr; si[c] = xi;
    float wr = lpow[2*p], wi = lpow[2*p+1];
    for (int s=1; s<NCHUNK; s<<=1){
        __syncthreads();
        float ur = 0.f, ui = 0.f;
        if (c >= s){ ur = sr[c-s]; ui = si[c-s]; }
        __syncthreads();
        xr += wr*ur - wi*ui;
        xi += wr*ui + wi*ur;
        sr[c] = xr; si[c] = xi;
        float t = wr*wr - wi*wi; wi = 2.f*wr*wi; wr = t;
    }
    __syncthreads();
    float er = 0.f, ei = 0.f;
    if (c > 0){ er = sr[c-1]; ei = si[c-1]; }
    agg[((size_t)c*P_DIM + p)*2]     = er;
    agg[((size_t)c*P_DIM + p)*2 + 1] = ei;
}

// ---------------- scan phase 3: apply + emit bf16 pairs ----------------------
__global__ __launch_bounds__(512)
void k_apply(const unsigned int* __restrict__ Bu, const float* __restrict__ lam,
             const float* __restrict__ xinit, unsigned int* __restrict__ xs)
{
    int p = threadIdx.x, c = blockIdx.x;
    float lrr = lam[2*p], lii = lam[2*p+1];
    float xr = xinit[((size_t)c*P_DIM + p)*2];
    float xi = xinit[((size_t)c*P_DIM + p)*2 + 1];
    const unsigned int* b2 = Bu + (size_t)c*CHUNK*512 + p;
    unsigned int* o = xs + (size_t)c*CHUNK*512 + p;
    #pragma unroll 4
    for (int t=0;t<CHUNK;t++){
        unsigned int b = b2[(size_t)t*512];
        float br = __uint_as_float(b << 16);
        float bi = __uint_as_float(b & 0xffff0000u);
        float tr = lrr*xr - lii*xi + br;
        xi = lrr*xi + lii*xr + bi;
        xr = tr;
        o[(size_t)t*512] = (unsigned int)f2bf(xr) | ((unsigned int)f2bf(xi) << 16);
    }
}

extern "C" void kernel_launch(void* const* d_in, const int* in_sizes, int n_in,
                              void* d_out, int out_size, void* d_ws, size_t ws_size,
                              hipStream_t stream)
{
    const float* u   = (const float*)d_in[0];
    const float* lre = (const float*)d_in[1];
    const float* lim = (const float*)d_in[2];
    const float* B   = (const float*)d_in[3];
    const float* C   = (const float*)d_in[4];
    const float* D   = (const float*)d_in[5];
    const float* ls  = (const float*)d_in[6];
    float* out = (float*)d_out;

    char* w = (char*)d_ws;
    unsigned short* u16  = (unsigned short*)(w + 0);          // 32 MiB
    unsigned short* xs16 = (unsigned short*)(w + 33554432);   // 32 MiB
    unsigned short* Bu16 = (unsigned short*)(w + 67108864);   // 32 MiB
    unsigned short* BB   = (unsigned short*)(w + 100663296);  // 2 MiB
    unsigned short* CC   = (unsigned short*)(w + 102760448);  // 2 MiB
    float* lam   = (float*)(w + 104857600);
    float* coef  = (float*)(w + 104861696);
    float* lpow  = (float*)(w + 104865792);
    float* agg   = (float*)(w + 104869888);                   // 1 MiB (xinit in place)
    float* wtab  = (float*)(w + 105918464);                   // 256 KiB

    k_prep_lambda<<<1, P_DIM, 0, stream>>>(lre, lim, ls, lam, coef, lpow, wtab);
    k_prep_misc<<<12288, 256, 0, stream>>>(B, C, coef, BB, CC, (const float4*)u, u16);

    // gemm1: Bu16 = bf16(u16 @ BB^T) + fused per-chunk aggregates -> agg
    gemm256<0><<<256, 512, 0, stream>>>(u16, BB, nullptr, Bu16, nullptr, nullptr,
                                        wtab, agg);

    k_scan<<<P_DIM, NCHUNK, 0, stream>>>(agg, lpow);
    k_apply<<<NCHUNK, P_DIM, 0, stream>>>((const unsigned int*)Bu16, lam, agg,
                                          (unsigned int*)xs16);

    // gemm2: out = xs16 @ CC^T + D*u
    gemm256<1><<<256, 512, 0, stream>>>(xs16, CC, out, nullptr, D, u16,
                                        nullptr, nullptr);
}